// Round 1
// 9200.397 us; speedup vs baseline: 2.3031x; 2.3031x over previous
//
#include <hip/hip_runtime.h>
#include <math.h>

typedef __attribute__((ext_vector_type(8))) short short8;
typedef __attribute__((ext_vector_type(4))) float floatx4;
typedef unsigned short ushort_t;
typedef unsigned int uint32;

#define BB 256
#define TT 250
#define NS 500
#define HH 512
#define TNS (TT * NS)
#define NBLK 256
#define TBLK 256
#define PL_USH 131072u      // act plane: 16ch*16ct*64lane*8 ushorts (512K x 256 bf16)
#define CH_USH 8192u        // act chunk stride: 16ct*64*8
// LDS: whi 64KB + wlo 64KB + scratch 2*32*65 floats
#define WHI_USH 32768
#define SCR_OFF 131072
#define SMEMB (131072 + 2 * 32 * 65 * 4)   // 147712 B

// ---- bf16 split helpers (RNE) ----
__device__ __forceinline__ ushort_t f2bf(float f) {
    uint32 u = __float_as_uint(f);
    u += 0x7fffu + ((u >> 16) & 1u);
    return (ushort_t)(u >> 16);
}
__device__ __forceinline__ float bf2f(ushort_t h) { return __uint_as_float(((uint32)h) << 16); }
__device__ __forceinline__ float sigm(float x) { return 1.f / (1.f + expf(-x)); }
__device__ __forceinline__ floatx4 mfma16(short8 a, short8 b, floatx4 c) {
    return __builtin_amdgcn_mfma_f32_16x16x32_bf16(a, b, c, 0, 0, 0);
}

// ------------- radix-16 dissemination barrier: 2 rounds, 15 partners/round -------------
// ONE flag per block (64B padded), monotonic value = phase*2 + round.
// Relaxed polls (sc1, no buffer_inv per poll!); exactly one release fence (wbl2)
// before signaling and one acquire fence (inv) after the last round.
__device__ __forceinline__ void dbar(unsigned* flags, unsigned phase, int bid) {
    const int tj = threadIdx.x;
    const unsigned v0 = phase << 1, v1 = (phase << 1) | 1u;
    __syncthreads();   // all block stores drained to L2 (implied vmcnt wait)
    if (tj == 0) {
        __builtin_amdgcn_fence(__ATOMIC_RELEASE, "agent");   // single wbl2: flush pk/x writes
        __hip_atomic_store(flags + ((size_t)bid << 4), v0,
                           __ATOMIC_RELAXED, __HIP_MEMORY_SCOPE_AGENT);
    }
    if (tj >= 1 && tj < 16) {
        unsigned* sp = flags + ((size_t)((bid - tj) & 255) << 4);
        while (__hip_atomic_load(sp, __ATOMIC_RELAXED, __HIP_MEMORY_SCOPE_AGENT) < v0)
            __builtin_amdgcn_s_sleep(2);
    }
    __syncthreads();
    if (tj == 0) {
        __hip_atomic_store(flags + ((size_t)bid << 4), v1,
                           __ATOMIC_RELAXED, __HIP_MEMORY_SCOPE_AGENT);
    }
    if (tj >= 1 && tj < 16) {
        unsigned* sp = flags + ((size_t)((bid - (tj << 4)) & 255) << 4);
        while (__hip_atomic_load(sp, __ATOMIC_RELAXED, __HIP_MEMORY_SCOPE_AGENT) < v1)
            __builtin_amdgcn_s_sleep(2);
    }
    __syncthreads();
    // one acquire fence per wave: inv L1 + L2 so fresh remote data is visible
    __builtin_amdgcn_fence(__ATOMIC_ACQUIRE, "agent");
}

// ---------------- block reductions (256 thr = 4 waves) ----------------
__device__ __forceinline__ float block_max4(float v, float* scr) {
#pragma unroll
    for (int off = 32; off; off >>= 1) v = fmaxf(v, __shfl_down(v, off, 64));
    if ((threadIdx.x & 63) == 0) scr[threadIdx.x >> 6] = v;
    __syncthreads();
    if (threadIdx.x == 0)
        scr[8] = fmaxf(fmaxf(scr[0], scr[1]), fmaxf(scr[2], scr[3]));
    __syncthreads();
    float r = scr[8];
    __syncthreads();
    return r;
}
__device__ __forceinline__ float2 block_sum2_4(float a, float b, float* scr) {
#pragma unroll
    for (int off = 32; off; off >>= 1) {
        a += __shfl_down(a, off, 64);
        b += __shfl_down(b, off, 64);
    }
    if ((threadIdx.x & 63) == 0) { int w = threadIdx.x >> 6; scr[w] = a; scr[4 + w] = b; }
    __syncthreads();
    if (threadIdx.x == 0) {
        scr[8] = scr[0] + scr[1] + scr[2] + scr[3];
        scr[9] = scr[4] + scr[5] + scr[6] + scr[7];
    }
    __syncthreads();
    float2 r = make_float2(scr[8], scr[9]);
    __syncthreads();
    return r;
}

// ------------- fused gi+gh GEMM: 32 chunks of K=32, depth-6 B prefetch (8-slot ring) ----
// gp: gi act B-frag base (pre-offset to this wave's first col-tile, hi plane; lo at +PL_USH)
// hp: gh act B-frag base (same layout)
// whiS/wloS: LDS W frag bases (pre-offset by lane*8); chunk c uses weight cols wc=2c,2c+1
__device__ __forceinline__ void gemm_both(const ushort_t* __restrict__ gp,
                                          const ushort_t* __restrict__ hp,
                                          const ushort_t* whiS, const ushort_t* wloS,
                                          floatx4 (&aGI)[2][2], floatx4 (&aGH)[2][2]) {
    constexpr int PF = 6;
    short8 Bh0[8], Bh1[8], Bl0[8], Bl1[8];
#pragma unroll
    for (int pc = 0; pc < PF; ++pc) {   // PF < 16, all from gi source
        const ushort_t* p = gp + (size_t)pc * CH_USH;
        Bh0[pc] = *(const short8*)(p);
        Bh1[pc] = *(const short8*)(p + 512);
        Bl0[pc] = *(const short8*)(p + PL_USH);
        Bl1[pc] = *(const short8*)(p + PL_USH + 512);
    }
#pragma unroll
    for (int c = 0; c < 32; ++c) {
        if (c < 32 - PF) {
            const int pc = c + PF;
            const ushort_t* p = (pc < 16) ? (gp + (size_t)pc * CH_USH)
                                          : (hp + (size_t)(pc - 16) * CH_USH);
            const int sl = pc & 7;
            Bh0[sl] = *(const short8*)(p);
            Bh1[sl] = *(const short8*)(p + 512);
            Bl0[sl] = *(const short8*)(p + PL_USH);
            Bl1[sl] = *(const short8*)(p + PL_USH + 512);
        }
        const int wc = c * 2;
        short8 w0h = *(const short8*)(whiS + (size_t)wc * 512);
        short8 w1h = *(const short8*)(whiS + (size_t)(wc + 1) * 512);
        short8 w0l = *(const short8*)(wloS + (size_t)wc * 512);
        short8 w1l = *(const short8*)(wloS + (size_t)(wc + 1) * 512);
        const int cs = c & 7;
        floatx4 (*A)[2] = (c < 16) ? aGI : aGH;
        // round-robin across the 4 accumulators to break dependency chains
        A[0][0] = mfma16(w0h, Bh0[cs], A[0][0]);
        A[0][1] = mfma16(w0h, Bh1[cs], A[0][1]);
        A[1][0] = mfma16(w1h, Bh0[cs], A[1][0]);
        A[1][1] = mfma16(w1h, Bh1[cs], A[1][1]);
        A[0][0] = mfma16(w0h, Bl0[cs], A[0][0]);
        A[0][1] = mfma16(w0h, Bl1[cs], A[0][1]);
        A[1][0] = mfma16(w1h, Bl0[cs], A[1][0]);
        A[1][1] = mfma16(w1h, Bl1[cs], A[1][1]);
        A[0][0] = mfma16(w0l, Bh0[cs], A[0][0]);
        A[0][1] = mfma16(w0l, Bh1[cs], A[0][1]);
        A[1][0] = mfma16(w1l, Bh0[cs], A[1][0]);
        A[1][1] = mfma16(w1l, Bh1[cs], A[1][1]);
    }
}

// ---------------- main persistent kernel ----------------
// 256 blocks = L(2) x UG(64 groups of 8 units) x CT(2 col-halves of 128).
// Each block: full GRU cell for its 8 units x 128 batches per step. One barrier/step.
__global__ void __launch_bounds__(TBLK, 1)
gru_main(const float* __restrict__ x,
         const float* __restrict__ wih0, const float* __restrict__ whh0,
         const float* __restrict__ bi0,  const float* __restrict__ bh0,
         const float* __restrict__ wih1, const float* __restrict__ whh1,
         const float* __restrict__ bi1,  const float* __restrict__ bh1,
         const float* __restrict__ fcb,  const float* __restrict__ fcT,
         ushort_t* xpack, ushort_t* h0pack, ushort_t* h1pack,
         unsigned* flags,
         float* __restrict__ out)
{
    extern __shared__ char smem_raw[];
    ushort_t* whi = (ushort_t*)smem_raw;            // 32768 ush (64 KB)
    ushort_t* wlo = whi + WHI_USH;                  // 64 KB
    float* scrF = (float*)(smem_raw + SCR_OFF);     // [2][32][65] floats

    const int bid = blockIdx.x, tid = threadIdx.x;
    const int L  = bid >> 7;
    const int UG = (bid >> 1) & 63;      // 8-unit group
    const int CT = bid & 1;              // col half (128 batches)
    const int wid = tid >> 6, lane = tid & 63;
    const int q = lane >> 4, n = lane & 15;

    // ---- stage this block's weights into LDS (hi+lo planes, A-frag layout) ----
    {
        const float* Wgi = L ? wih1 : wih0;
        const float* Wgh = L ? whh1 : whh0;
        const int Kgi = L ? HH : NS;
        for (int idx = tid; idx < 32768; idx += TBLK) {
            const int j = idx & 7, ln = (idx >> 3) & 63, rc = idx >> 9;  // rc = wc*2+rt
            const int c = rc >> 1, rt = rc & 1;
            const int m = ln & 15, qq = ln >> 4;
            const int lr = rt * 16 + m;          // 0..31 (rows 24..31 pad)
            const int g = lr >> 3, u = lr & 7;
            float v = 0.f;
            if (g < 3) {
                if (c < 16) {
                    const int k = c * 32 + qq * 8 + j;
                    if (k < Kgi) v = Wgi[(size_t)(g * HH + UG * 8 + u) * Kgi + k];
                } else {
                    const int k = (c - 16) * 32 + qq * 8 + j;
                    v = Wgh[(size_t)(g * HH + UG * 8 + u) * HH + k];
                }
            }
            const ushort_t hb = f2bf(v);
            whi[idx] = hb;
            wlo[idx] = f2bf(v - bf2f(hb));
        }
    }

    // per-thread elementwise assignment: units u2,u2+1; cols h*64 + lb (h=round)
    const int lb = tid & 63, u2 = (tid >> 6) * 2;
    float biR[2], biZ[2], biN[2], bhR[2], bhZ[2], bhN[2];
    {
        const float* bi = L ? bi1 : bi0;
        const float* bh = L ? bh1 : bh0;
#pragma unroll
        for (int p = 0; p < 2; ++p) {
            const int ugl = UG * 8 + u2 + p;
            biR[p] = bi[ugl]; biZ[p] = bi[HH + ugl]; biN[p] = bi[2 * HH + ugl];
            bhR[p] = bh[ugl]; bhZ[p] = bh[HH + ugl]; bhN[p] = bh[2 * HH + ugl];
        }
    }
    float hreg[4] = {0.f, 0.f, 0.f, 0.f};   // [round h][p]
    const int chW = UG >> 2, qqW = UG & 3;  // pack-write constants
    __syncthreads();

    const ushort_t* whiS = whi + (size_t)lane * 8;
    const ushort_t* wloS = wlo + (size_t)lane * 8;
    const size_t apoff = ((size_t)(CT * 8 + wid * 2) * 64 + lane) * 8;

    unsigned phase = 0;
    for (int s = 0; s <= TT; ++s) {
        const bool active = L ? (s >= 1) : (s < TT);
        if (active) {
            const ushort_t *gisrc, *ghsrc;
            if (L == 0) {
                gisrc = xpack + (size_t)(s & 1) * 2 * PL_USH;
                ghsrc = h0pack + (size_t)((s - 1) & 1) * 2 * PL_USH;
            } else {
                gisrc = h0pack + (size_t)((s - 1) & 1) * 2 * PL_USH;
                ghsrc = h1pack + (size_t)(s & 1) * 2 * PL_USH;
            }
            floatx4 z4 = {0.f, 0.f, 0.f, 0.f};
            floatx4 aGI[2][2], aGH[2][2];
#pragma unroll
            for (int i = 0; i < 2; ++i) { aGI[i][0] = z4; aGI[i][1] = z4; aGH[i][0] = z4; aGH[i][1] = z4; }
            gemm_both(gisrc + apoff, ghsrc + apoff, whiS, wloS, aGI, aGH);

            // ---- x staging loads for step s+1 (issue early, store later) ----
            float4 xv0, xv1;
            const bool doX = (s <= TT - 2) && (bid * TBLK + tid < 16384);
            int xko = 0, xb = 0;
            if (doX) {
                const int gx = bid * TBLK + tid;
                xko = gx & 63; xb = gx >> 6;
                const float* xs = x + ((size_t)xb * TT + (s + 1)) * NS + xko * 8;
                if (xko < 62) { xv0 = *(const float4*)(xs); xv1 = *(const float4*)(xs + 4); }
                else {  // ko 62: k 496..499 valid; ko 63: none
                    float tmp[8];
#pragma unroll
                    for (int j = 0; j < 8; ++j) {
                        const int k = xko * 8 + j;
                        tmp[j] = (k < NS) ? xs[j] : 0.f;
                    }
                    xv0 = make_float4(tmp[0], tmp[1], tmp[2], tmp[3]);
                    xv1 = make_float4(tmp[4], tmp[5], tmp[6], tmp[7]);
                }
            }

            // ---- elementwise in two col-rounds through LDS scratch ----
            ushort_t* pk = L ? h1pack + (size_t)((s - 1) & 1) * 2 * PL_USH
                             : h0pack + (size_t)(s & 1) * 2 * PL_USH;
#pragma unroll
            for (int h = 0; h < 2; ++h) {
                if ((wid >> 1) == h) {
#pragma unroll
                    for (int rt = 0; rt < 2; ++rt)
#pragma unroll
                        for (int t = 0; t < 2; ++t) {
                            const int row0 = rt * 16 + q * 4;
                            const int colr = ((wid & 1) * 2 + t) * 16 + n;
#pragma unroll
                            for (int r4 = 0; r4 < 4; ++r4) {
                                scrF[(row0 + r4) * 65 + colr] = aGI[rt][t][r4];
                                scrF[2080 + (row0 + r4) * 65 + colr] = aGH[rt][t][r4];
                            }
                        }
                }
                __syncthreads();
#pragma unroll
                for (int p = 0; p < 2; ++p) {
                    const int u = u2 + p;
                    const float gir = scrF[u * 65 + lb],        ghr = scrF[2080 + u * 65 + lb];
                    const float giz = scrF[(8 + u) * 65 + lb],  ghz = scrF[2080 + (8 + u) * 65 + lb];
                    const float gin = scrF[(16 + u) * 65 + lb], ghn = scrF[2080 + (16 + u) * 65 + lb];
                    const float rr = sigm(gir + biR[p] + ghr + bhR[p]);
                    const float zz = sigm(giz + biZ[p] + ghz + bhZ[p]);
                    const float nn = tanhf(gin + biN[p] + rr * (ghn + bhN[p]));
                    const float hv = (1.f - zz) * nn + zz * hreg[h * 2 + p];
                    hreg[h * 2 + p] = hv;
                    const int b = CT * 128 + h * 64 + lb;
                    const size_t o = ((size_t)(chW * 16 + (b >> 4)) * 64 + qqW * 16 + (b & 15)) * 8 + u;
                    const ushort_t hb = f2bf(hv);
                    pk[o] = hb;
                    pk[PL_USH + o] = f2bf(hv - bf2f(hb));
                }
                __syncthreads();
            }

            // ---- x staging stores ----
            if (doX) {
                ushort_t hi8[8], lo8[8];
                float vv[8] = {xv0.x, xv0.y, xv0.z, xv0.w, xv1.x, xv1.y, xv1.z, xv1.w};
#pragma unroll
                for (int j = 0; j < 8; ++j) {
                    hi8[j] = f2bf(vv[j]);
                    lo8[j] = f2bf(vv[j] - bf2f(hi8[j]));
                }
                ushort_t* xp = xpack + (size_t)((s + 1) & 1) * 2 * PL_USH;
                const size_t o = ((size_t)((xko >> 2) * 16 + (xb >> 4)) * 64 + (xko & 3) * 16 + (xb & 15)) * 8;
                *(uint4*)(xp + o) = *(uint4*)hi8;
                *(uint4*)(xp + PL_USH + o) = *(uint4*)lo8;
            }
        } else if ((s <= TT - 2) && (bid * TBLK + tid < 16384)) {
            // inactive blocks still stage x
            const int gx = bid * TBLK + tid;
            const int xko = gx & 63, xb = gx >> 6;
            const float* xs = x + ((size_t)xb * TT + (s + 1)) * NS + xko * 8;
            ushort_t hi8[8], lo8[8];
#pragma unroll
            for (int j = 0; j < 8; ++j) {
                const int k = xko * 8 + j;
                const float v = (k < NS) ? xs[j] : 0.f;
                hi8[j] = f2bf(v);
                lo8[j] = f2bf(v - bf2f(hi8[j]));
            }
            ushort_t* xp = xpack + (size_t)((s + 1) & 1) * 2 * PL_USH;
            const size_t o = ((size_t)((xko >> 2) * 16 + (xb >> 4)) * 64 + (xko & 3) * 16 + (xb & 15)) * 8;
            *(uint4*)(xp + o) = *(uint4*)hi8;
            *(uint4*)(xp + PL_USH + o) = *(uint4*)lo8;
        }
        ++phase;
        dbar(flags, phase, bid);
    }

    // ================= epilogue: FC + silu + softmax + rebalance (block = batch) =========
    {
        const int b = bid;
        float* sh = (float*)smem_raw;       // 512 floats
        float* scr = sh + 576;
        const ushort_t* pk = h1pack + (size_t)1 * 2 * PL_USH;   // h1[249], parity 1
        for (int u = tid; u < HH; u += TBLK) {
            const int uo = u >> 3, j = u & 7;
            const size_t o = ((size_t)((uo >> 2) * 16 + (b >> 4)) * 64 + (uo & 3) * 16 + (b & 15)) * 8 + j;
            sh[u] = bf2f(pk[o]) + bf2f(pk[PL_USH + o]);
        }
        __syncthreads();

        const int o1 = tid;
        const bool v2 = (tid + 256) < NS;
        const int o2 = v2 ? (tid + 256) : (NS - 1);
        float a0 = fcb[o1], a1 = fcb[o2];
        for (int k = 0; k < HH; ++k) {
            const float hv = sh[k];
            const float* fr = fcT + (size_t)k * NS;
            a0 = fmaf(hv, fr[o1], a0);
            a1 = fmaf(hv, fr[o2], a1);
        }
        float l0 = a0 * sigm(a0);
        float l1 = a1 * sigm(a1);
        float mx = block_max4(fmaxf(l0, v2 ? l1 : -3.4e38f), scr);
        float e0 = expf(l0 - mx);
        float e1 = v2 ? expf(l1 - mx) : 0.f;
        float2 s2 = block_sum2_4(e0 + e1, 0.f, scr);
        float w0 = e0 / s2.x, w1 = e1 / s2.x;
        for (int it = 0; it < 30; ++it) {
            float c0v = fminf(fmaxf(w0, 0.f), 0.1f);
            float c1v = fminf(fmaxf(w1, 0.f), 0.1f);
            float lv = (w0 - c0v) + (w1 - c1v);
            float n0 = (c0v != 0.1f) ? c0v : 0.f;
            float n1 = (v2 && c1v != 0.1f) ? c1v : 0.f;
            float2 rs = block_sum2_4(lv, n0 + n1, scr);
            float inv = rs.x / rs.y;
            w0 = c0v + inv * n0;
            w1 = c1v + inv * n1;
        }
        out[(size_t)b * NS + o1] = w0;
        if (v2) out[(size_t)b * NS + tid + 256] = w1;
    }
}

// ---------------- prep: pack x[t=0] ----------------
__global__ void pack_x0(const float* __restrict__ x, ushort_t* __restrict__ xpack) {
    const int t = blockIdx.x * 256 + threadIdx.x;   // 16384 threads
    const int ko = t & 63, b = t >> 6;
    const float* xs = x + (size_t)b * TT * NS;      // t=0
    ushort_t hi8[8], lo8[8];
#pragma unroll
    for (int j = 0; j < 8; ++j) {
        const int k = ko * 8 + j;
        const float v = (k < NS) ? xs[k] : 0.f;
        hi8[j] = f2bf(v);
        lo8[j] = f2bf(v - bf2f(hi8[j]));
    }
    const size_t o = ((size_t)((ko >> 2) * 16 + (b >> 4)) * 64 + (ko & 3) * 16 + (b & 15)) * 8;
    *(uint4*)(xpack + o) = *(uint4*)hi8;
    *(uint4*)(xpack + PL_USH + o) = *(uint4*)lo8;
}

// ---------------- prep: fc weight transpose ----------------
__global__ void transpose_k(const float* __restrict__ src, float* __restrict__ dst,
                            int G, int K) {
    int idx = blockIdx.x * 256 + threadIdx.x;
    if (idx >= G * K) return;
    int k = idx / G, g = idx - k * G;
    dst[idx] = src[(size_t)g * K + k];
}

// ---------------- launch ----------------
extern "C" void kernel_launch(void* const* d_in, const int* in_sizes, int n_in,
                              void* d_out, int out_size, void* d_ws, size_t ws_size,
                              hipStream_t stream) {
    const float* x    = (const float*)d_in[0];
    const float* wih0 = (const float*)d_in[1];
    const float* whh0 = (const float*)d_in[2];
    const float* bih0 = (const float*)d_in[3];
    const float* bhh0 = (const float*)d_in[4];
    const float* wih1 = (const float*)d_in[5];
    const float* whh1 = (const float*)d_in[6];
    const float* bih1 = (const float*)d_in[7];
    const float* bhh1 = (const float*)d_in[8];
    const float* fcw  = (const float*)d_in[9];
    const float* fcb  = (const float*)d_in[10];
    float* outp = (float*)d_out;

    // ws layout (~4.4 MB):
    char* ws = (char*)d_ws;
    unsigned* flags  = (unsigned*)ws;                         // 256*64B used (region 196608)
    ushort_t* h0pack = (ushort_t*)(ws + 196608);              // 1 MB
    ushort_t* h1pack = (ushort_t*)(ws + 196608 + 1048576);    // 1 MB
    ushort_t* xpack  = (ushort_t*)(ws + 196608 + 2097152);    // 1 MB
    float*    fcT    = (float*)(ws + 196608 + 3145728);       // 512*500*4 = 1024000

    // zero: flags + h packs (h0 = 0 both parities)
    hipMemsetAsync(ws, 0, 196608 + 2097152, stream);
    pack_x0<<<64, 256, 0, stream>>>(x, xpack);
    {
        int nel = NS * HH;
        transpose_k<<<(nel + 255) / 256, 256, 0, stream>>>(fcw, fcT, NS, HH);
    }

    hipFuncSetAttribute((const void*)gru_main,
                        hipFuncAttributeMaxDynamicSharedMemorySize, SMEMB);

    void* args[] = {(void*)&x,
                    (void*)&wih0, (void*)&whh0, (void*)&bih0, (void*)&bhh0,
                    (void*)&wih1, (void*)&whh1, (void*)&bih1, (void*)&bhh1,
                    (void*)&fcb, (void*)&fcT,
                    (void*)&xpack, (void*)&h0pack, (void*)&h1pack,
                    (void*)&flags, (void*)&outp};
    hipError_t e = hipLaunchCooperativeKernel((const void*)gru_main, dim3(NBLK), dim3(TBLK),
                                              args, SMEMB, stream);
    if (e != hipSuccess) {
        gru_main<<<dim3(NBLK), dim3(TBLK), SMEMB, stream>>>(
            x, wih0, whh0, bih0, bhh0, wih1, whh1, bih1, bhh1,
            fcb, fcT, xpack, h0pack, h1pack, flags, outp);
    }
}

// Round 2
// 5804.474 us; speedup vs baseline: 3.6506x; 1.5851x over previous
//
#include <hip/hip_runtime.h>
#include <math.h>

typedef __attribute__((ext_vector_type(8))) short short8;
typedef __attribute__((ext_vector_type(4))) float floatx4;
typedef unsigned short ushort_t;
typedef unsigned int uint32;
typedef unsigned long long u64;

#define BB 256
#define TT 250
#define NS 500
#define HH 512
#define TNS (TT * NS)
#define NBLK 256
#define TBLK 256
#define PL_USH 131072u      // act plane: 16ch*16ct*64lane*8 ushorts (512K x 256 bf16)
#define CH_USH 8192u        // act chunk stride: 16ct*64*8
// LDS: whi 64KB + wlo 64KB + scratch 2*32*65 floats
#define WHI_USH 32768
#define SCR_OFF 131072
#define SMEMB (131072 + 2 * 32 * 65 * 4)   // 147712 B

// ---- bf16 split helpers (RNE) ----
__device__ __forceinline__ ushort_t f2bf(float f) {
    uint32 u = __float_as_uint(f);
    u += 0x7fffu + ((u >> 16) & 1u);
    return (ushort_t)(u >> 16);
}
__device__ __forceinline__ float bf2f(ushort_t h) { return __uint_as_float(((uint32)h) << 16); }
__device__ __forceinline__ float sigm(float x) { return 1.f / (1.f + expf(-x)); }
__device__ __forceinline__ floatx4 mfma16(short8 a, short8 b, floatx4 c) {
    return __builtin_amdgcn_mfma_f32_16x16x32_bf16(a, b, c, 0, 0, 0);
}
__device__ __forceinline__ u64 pack4(const ushort_t* a) {
    return (u64)a[0] | ((u64)a[1] << 16) | ((u64)a[2] << 32) | ((u64)a[3] << 48);
}
__device__ __forceinline__ void st_agent_u32(ushort_t* p, uint32 v) {
    __hip_atomic_store((uint32*)p, v, __ATOMIC_RELAXED, __HIP_MEMORY_SCOPE_AGENT);
}
__device__ __forceinline__ void st_agent_u64(ushort_t* p, u64 v) {
    __hip_atomic_store((u64*)p, v, __ATOMIC_RELAXED, __HIP_MEMORY_SCOPE_AGENT);
}

// ------------- radix-16 dissemination barrier + per-XCD leader invalidation -------------
// All cross-block data stores in the loop are sc1 write-through (relaxed agent atomics),
// so NO release wbl2 is needed: compiler's vmcnt(0) before s_barrier drains them.
// After global arrival, ONE leader block per XCD does buffer_inv sc1 (L1+L2) and posts a
// per-XCD flag in L3; other blocks poll it (sc1 load) and flash-inv only their CU's L1.
__device__ __forceinline__ void dbar(unsigned* flags, unsigned phase, int bid,
                                     int myxcd, bool isLead) {
    const int tj = threadIdx.x;
    const unsigned v0 = phase << 1, v1 = (phase << 1) | 1u;
    unsigned* xflags = flags + 4096;   // per-XCD inv-done flags (64B slots)
    __syncthreads();   // drains this block's pack stores (vmcnt(0) before s_barrier)
    if (tj == 0)
        __hip_atomic_store(flags + ((size_t)bid << 4), v0,
                           __ATOMIC_RELAXED, __HIP_MEMORY_SCOPE_AGENT);
    if (tj >= 1 && tj < 16) {
        unsigned* sp = flags + ((size_t)((bid - tj) & 255) << 4);
        while (__hip_atomic_load(sp, __ATOMIC_RELAXED, __HIP_MEMORY_SCOPE_AGENT) < v0)
            __builtin_amdgcn_s_sleep(2);
    }
    __syncthreads();
    if (tj == 0)
        __hip_atomic_store(flags + ((size_t)bid << 4), v1,
                           __ATOMIC_RELAXED, __HIP_MEMORY_SCOPE_AGENT);
    if (tj >= 1 && tj < 16) {
        unsigned* sp = flags + ((size_t)((bid - (tj << 4)) & 255) << 4);
        while (__hip_atomic_load(sp, __ATOMIC_RELAXED, __HIP_MEMORY_SCOPE_AGENT) < v1)
            __builtin_amdgcn_s_sleep(2);
    }
    __syncthreads();
    if (isLead) {
        if (tj == 0) {
            // single L2(+L1) invalidation for this XCD, then publish
            __builtin_amdgcn_fence(__ATOMIC_ACQUIRE, "agent");
            __hip_atomic_store(xflags + ((size_t)myxcd << 4), phase,
                               __ATOMIC_RELAXED, __HIP_MEMORY_SCOPE_AGENT);
        }
    } else {
        if (tj == 0) {
            unsigned* sp = xflags + ((size_t)myxcd << 4);
            while (__hip_atomic_load(sp, __ATOMIC_RELAXED, __HIP_MEMORY_SCOPE_AGENT) < phase)
                __builtin_amdgcn_s_sleep(2);
        }
        if (tj < 64) asm volatile("buffer_inv" ::: "memory");  // CU vector-L1 inv only
    }
    __syncthreads();
}

// ---------------- block reductions (256 thr = 4 waves) ----------------
__device__ __forceinline__ float block_max4(float v, float* scr) {
#pragma unroll
    for (int off = 32; off; off >>= 1) v = fmaxf(v, __shfl_down(v, off, 64));
    if ((threadIdx.x & 63) == 0) scr[threadIdx.x >> 6] = v;
    __syncthreads();
    if (threadIdx.x == 0)
        scr[8] = fmaxf(fmaxf(scr[0], scr[1]), fmaxf(scr[2], scr[3]));
    __syncthreads();
    float r = scr[8];
    __syncthreads();
    return r;
}
__device__ __forceinline__ float2 block_sum2_4(float a, float b, float* scr) {
#pragma unroll
    for (int off = 32; off; off >>= 1) {
        a += __shfl_down(a, off, 64);
        b += __shfl_down(b, off, 64);
    }
    if ((threadIdx.x & 63) == 0) { int w = threadIdx.x >> 6; scr[w] = a; scr[4 + w] = b; }
    __syncthreads();
    if (threadIdx.x == 0) {
        scr[8] = scr[0] + scr[1] + scr[2] + scr[3];
        scr[9] = scr[4] + scr[5] + scr[6] + scr[7];
    }
    __syncthreads();
    float2 r = make_float2(scr[8], scr[9]);
    __syncthreads();
    return r;
}

// ------------- fused gi+gh GEMM: 32 chunks of K=32, depth-6 B prefetch (8-slot ring) ----
__device__ __forceinline__ void gemm_both(const ushort_t* __restrict__ gp,
                                          const ushort_t* __restrict__ hp,
                                          const ushort_t* whiS, const ushort_t* wloS,
                                          floatx4 (&aGI)[2][2], floatx4 (&aGH)[2][2]) {
    constexpr int PF = 6;
    short8 Bh0[8], Bh1[8], Bl0[8], Bl1[8];
#pragma unroll
    for (int pc = 0; pc < PF; ++pc) {   // PF < 16, all from gi source
        const ushort_t* p = gp + (size_t)pc * CH_USH;
        Bh0[pc] = *(const short8*)(p);
        Bh1[pc] = *(const short8*)(p + 512);
        Bl0[pc] = *(const short8*)(p + PL_USH);
        Bl1[pc] = *(const short8*)(p + PL_USH + 512);
    }
#pragma unroll
    for (int c = 0; c < 32; ++c) {
        if (c < 32 - PF) {
            const int pc = c + PF;
            const ushort_t* p = (pc < 16) ? (gp + (size_t)pc * CH_USH)
                                          : (hp + (size_t)(pc - 16) * CH_USH);
            const int sl = pc & 7;
            Bh0[sl] = *(const short8*)(p);
            Bh1[sl] = *(const short8*)(p + 512);
            Bl0[sl] = *(const short8*)(p + PL_USH);
            Bl1[sl] = *(const short8*)(p + PL_USH + 512);
        }
        const int wc = c * 2;
        short8 w0h = *(const short8*)(whiS + (size_t)wc * 512);
        short8 w1h = *(const short8*)(whiS + (size_t)(wc + 1) * 512);
        short8 w0l = *(const short8*)(wloS + (size_t)wc * 512);
        short8 w1l = *(const short8*)(wloS + (size_t)(wc + 1) * 512);
        const int cs = c & 7;
        floatx4 (*A)[2] = (c < 16) ? aGI : aGH;
        A[0][0] = mfma16(w0h, Bh0[cs], A[0][0]);
        A[0][1] = mfma16(w0h, Bh1[cs], A[0][1]);
        A[1][0] = mfma16(w1h, Bh0[cs], A[1][0]);
        A[1][1] = mfma16(w1h, Bh1[cs], A[1][1]);
        A[0][0] = mfma16(w0h, Bl0[cs], A[0][0]);
        A[0][1] = mfma16(w0h, Bl1[cs], A[0][1]);
        A[1][0] = mfma16(w1h, Bl0[cs], A[1][0]);
        A[1][1] = mfma16(w1h, Bl1[cs], A[1][1]);
        A[0][0] = mfma16(w0l, Bh0[cs], A[0][0]);
        A[0][1] = mfma16(w0l, Bh1[cs], A[0][1]);
        A[1][0] = mfma16(w1l, Bh0[cs], A[1][0]);
        A[1][1] = mfma16(w1l, Bh1[cs], A[1][1]);
    }
}

// ---------------- main persistent kernel ----------------
__global__ void __launch_bounds__(TBLK, 1)
gru_main(const float* __restrict__ x,
         const float* __restrict__ wih0, const float* __restrict__ whh0,
         const float* __restrict__ bi0,  const float* __restrict__ bh0,
         const float* __restrict__ wih1, const float* __restrict__ whh1,
         const float* __restrict__ bi1,  const float* __restrict__ bh1,
         const float* __restrict__ fcb,  const float* __restrict__ fcT,
         ushort_t* xpack, ushort_t* h0pack, ushort_t* h1pack,
         unsigned* flags,
         float* __restrict__ out)
{
    extern __shared__ char smem_raw[];
    ushort_t* whi = (ushort_t*)smem_raw;            // 32768 ush (64 KB)
    ushort_t* wlo = whi + WHI_USH;                  // 64 KB
    float* scrF = (float*)(smem_raw + SCR_OFF);     // [2][32][65] floats

    const int bid = blockIdx.x, tid = threadIdx.x;
    const int L  = bid >> 7;
    const int UG = (bid >> 1) & 63;      // 8-unit group
    const int CT = bid & 1;              // col half (128 batches)
    const int wid = tid >> 6, lane = tid & 63;
    const int q = lane >> 4, n = lane & 15;

    // ---- stage this block's weights into LDS (hi+lo planes, A-frag layout) ----
    {
        const float* Wgi = L ? wih1 : wih0;
        const float* Wgh = L ? whh1 : whh0;
        const int Kgi = L ? HH : NS;
        for (int idx = tid; idx < 32768; idx += TBLK) {
            const int j = idx & 7, ln = (idx >> 3) & 63, rc = idx >> 9;  // rc = wc*2+rt
            const int c = rc >> 1, rt = rc & 1;
            const int m = ln & 15, qq = ln >> 4;
            const int lr = rt * 16 + m;          // 0..31 (rows 24..31 pad)
            const int g = lr >> 3, u = lr & 7;
            float v = 0.f;
            if (g < 3) {
                if (c < 16) {
                    const int k = c * 32 + qq * 8 + j;
                    if (k < Kgi) v = Wgi[(size_t)(g * HH + UG * 8 + u) * Kgi + k];
                } else {
                    const int k = (c - 16) * 32 + qq * 8 + j;
                    v = Wgh[(size_t)(g * HH + UG * 8 + u) * HH + k];
                }
            }
            const ushort_t hb = f2bf(v);
            whi[idx] = hb;
            wlo[idx] = f2bf(v - bf2f(hb));
        }
    }

    // ---- per-XCD leader election (dispatch-mapping independent) ----
    int myxcd;
    asm volatile("s_getreg_b32 %0, hwreg(HW_REG_XCC_ID)" : "=s"(myxcd));
    myxcd &= 7;
    if (tid == 0) {
        unsigned old = atomicCAS(flags + 8192 + ((size_t)myxcd << 4), 0u, (unsigned)bid + 1u);
        scrF[0] = (old == 0u) ? 1.f : 0.f;
    }
    __syncthreads();
    const bool isLead = (scrF[0] != 0.f);

    // per-thread elementwise assignment: units u2,u2+1; cols h*64 + lb (h=round)
    const int lb = tid & 63, u2 = (tid >> 6) * 2;
    float biR[2], biZ[2], biN[2], bhR[2], bhZ[2], bhN[2];
    {
        const float* bi = L ? bi1 : bi0;
        const float* bh = L ? bh1 : bh0;
#pragma unroll
        for (int p = 0; p < 2; ++p) {
            const int ugl = UG * 8 + u2 + p;
            biR[p] = bi[ugl]; biZ[p] = bi[HH + ugl]; biN[p] = bi[2 * HH + ugl];
            bhR[p] = bh[ugl]; bhZ[p] = bh[HH + ugl]; bhN[p] = bh[2 * HH + ugl];
        }
    }
    float hreg[4] = {0.f, 0.f, 0.f, 0.f};   // [round h][p]
    const int chW = UG >> 2, qqW = UG & 3;  // pack-write constants
    __syncthreads();

    const ushort_t* whiS = whi + (size_t)lane * 8;
    const ushort_t* wloS = wlo + (size_t)lane * 8;
    const size_t apoff = ((size_t)(CT * 8 + wid * 2) * 64 + lane) * 8;

    unsigned phase = 0;
    for (int s = 0; s <= TT; ++s) {
        const bool active = L ? (s >= 1) : (s < TT);
        if (active) {
            const ushort_t *gisrc, *ghsrc;
            if (L == 0) {
                gisrc = xpack + (size_t)(s & 1) * 2 * PL_USH;
                ghsrc = h0pack + (size_t)((s - 1) & 1) * 2 * PL_USH;
            } else {
                gisrc = h0pack + (size_t)((s - 1) & 1) * 2 * PL_USH;
                ghsrc = h1pack + (size_t)(s & 1) * 2 * PL_USH;
            }
            floatx4 z4 = {0.f, 0.f, 0.f, 0.f};
            floatx4 aGI[2][2], aGH[2][2];
#pragma unroll
            for (int i = 0; i < 2; ++i) { aGI[i][0] = z4; aGI[i][1] = z4; aGH[i][0] = z4; aGH[i][1] = z4; }
            gemm_both(gisrc + apoff, ghsrc + apoff, whiS, wloS, aGI, aGH);

            // ---- x staging loads for step s+1 (issue early, store later) ----
            float4 xv0, xv1;
            const bool doX = (s <= TT - 2) && (bid * TBLK + tid < 16384);
            int xko = 0, xb = 0;
            if (doX) {
                const int gx = bid * TBLK + tid;
                xko = gx & 63; xb = gx >> 6;
                const float* xs = x + ((size_t)xb * TT + (s + 1)) * NS + xko * 8;
                if (xko < 62) { xv0 = *(const float4*)(xs); xv1 = *(const float4*)(xs + 4); }
                else {
                    float tmp[8];
#pragma unroll
                    for (int j = 0; j < 8; ++j) {
                        const int k = xko * 8 + j;
                        tmp[j] = (k < NS) ? xs[j] : 0.f;
                    }
                    xv0 = make_float4(tmp[0], tmp[1], tmp[2], tmp[3]);
                    xv1 = make_float4(tmp[4], tmp[5], tmp[6], tmp[7]);
                }
            }

            // ---- elementwise in two col-rounds through LDS scratch ----
            ushort_t* pk = L ? h1pack + (size_t)((s - 1) & 1) * 2 * PL_USH
                             : h0pack + (size_t)(s & 1) * 2 * PL_USH;
#pragma unroll
            for (int h = 0; h < 2; ++h) {
                if ((wid >> 1) == h) {
#pragma unroll
                    for (int rt = 0; rt < 2; ++rt)
#pragma unroll
                        for (int t = 0; t < 2; ++t) {
                            const int row0 = rt * 16 + q * 4;
                            const int colr = ((wid & 1) * 2 + t) * 16 + n;
#pragma unroll
                            for (int r4 = 0; r4 < 4; ++r4) {
                                scrF[(row0 + r4) * 65 + colr] = aGI[rt][t][r4];
                                scrF[2080 + (row0 + r4) * 65 + colr] = aGH[rt][t][r4];
                            }
                        }
                }
                __syncthreads();
                float hvv[2];
#pragma unroll
                for (int p = 0; p < 2; ++p) {
                    const int u = u2 + p;
                    const float gir = scrF[u * 65 + lb],        ghr = scrF[2080 + u * 65 + lb];
                    const float giz = scrF[(8 + u) * 65 + lb],  ghz = scrF[2080 + (8 + u) * 65 + lb];
                    const float gin = scrF[(16 + u) * 65 + lb], ghn = scrF[2080 + (16 + u) * 65 + lb];
                    const float rr = sigm(gir + biR[p] + ghr + bhR[p]);
                    const float zz = sigm(giz + biZ[p] + ghz + bhZ[p]);
                    const float nn = tanhf(gin + biN[p] + rr * (ghn + bhN[p]));
                    const float hv = (1.f - zz) * nn + zz * hreg[h * 2 + p];
                    hreg[h * 2 + p] = hv;
                    hvv[p] = hv;
                }
                // paired write-through stores (p0|p1 in one dword per plane)
                {
                    const int b = CT * 128 + h * 64 + lb;
                    const size_t o8 = ((size_t)(chW * 16 + (b >> 4)) * 64 + qqW * 16 + (b & 15)) * 8;
                    const ushort_t hb0 = f2bf(hvv[0]), hb1 = f2bf(hvv[1]);
                    const uint32 hi2 = (uint32)hb0 | ((uint32)hb1 << 16);
                    const uint32 lo2 = (uint32)f2bf(hvv[0] - bf2f(hb0)) |
                                       ((uint32)f2bf(hvv[1] - bf2f(hb1)) << 16);
                    st_agent_u32(pk + o8 + u2, hi2);
                    st_agent_u32(pk + PL_USH + o8 + u2, lo2);
                }
                __syncthreads();
            }

            // ---- x staging stores (write-through) ----
            if (doX) {
                ushort_t hi8[8], lo8[8];
                float vv[8] = {xv0.x, xv0.y, xv0.z, xv0.w, xv1.x, xv1.y, xv1.z, xv1.w};
#pragma unroll
                for (int j = 0; j < 8; ++j) {
                    hi8[j] = f2bf(vv[j]);
                    lo8[j] = f2bf(vv[j] - bf2f(hi8[j]));
                }
                ushort_t* xp = xpack + (size_t)((s + 1) & 1) * 2 * PL_USH;
                const size_t o = ((size_t)((xko >> 2) * 16 + (xb >> 4)) * 64 + (xko & 3) * 16 + (xb & 15)) * 8;
                st_agent_u64(xp + o, pack4(hi8));
                st_agent_u64(xp + o + 4, pack4(hi8 + 4));
                st_agent_u64(xp + PL_USH + o, pack4(lo8));
                st_agent_u64(xp + PL_USH + o + 4, pack4(lo8 + 4));
            }
        } else if ((s <= TT - 2) && (bid * TBLK + tid < 16384)) {
            // inactive blocks still stage x
            const int gx = bid * TBLK + tid;
            const int xko = gx & 63, xb = gx >> 6;
            const float* xs = x + ((size_t)xb * TT + (s + 1)) * NS + xko * 8;
            ushort_t hi8[8], lo8[8];
#pragma unroll
            for (int j = 0; j < 8; ++j) {
                const int k = xko * 8 + j;
                const float v = (k < NS) ? xs[j] : 0.f;
                hi8[j] = f2bf(v);
                lo8[j] = f2bf(v - bf2f(hi8[j]));
            }
            ushort_t* xp = xpack + (size_t)((s + 1) & 1) * 2 * PL_USH;
            const size_t o = ((size_t)((xko >> 2) * 16 + (xb >> 4)) * 64 + (xko & 3) * 16 + (xb & 15)) * 8;
            st_agent_u64(xp + o, pack4(hi8));
            st_agent_u64(xp + o + 4, pack4(hi8 + 4));
            st_agent_u64(xp + PL_USH + o, pack4(lo8));
            st_agent_u64(xp + PL_USH + o + 4, pack4(lo8 + 4));
        }
        ++phase;
        dbar(flags, phase, bid, myxcd, isLead);
    }

    // ================= epilogue: FC + silu + softmax + rebalance (block = batch) =========
    {
        const int b = bid;
        float* sh = (float*)smem_raw;       // 512 floats
        float* scr = sh + 576;
        const ushort_t* pk = h1pack + (size_t)1 * 2 * PL_USH;   // h1[249], parity 1
        for (int u = tid; u < HH; u += TBLK) {
            const int uo = u >> 3, j = u & 7;
            const size_t o = ((size_t)((uo >> 2) * 16 + (b >> 4)) * 64 + (uo & 3) * 16 + (b & 15)) * 8 + j;
            sh[u] = bf2f(pk[o]) + bf2f(pk[PL_USH + o]);
        }
        __syncthreads();

        const int o1 = tid;
        const bool v2 = (tid + 256) < NS;
        const int o2 = v2 ? (tid + 256) : (NS - 1);
        float a0 = fcb[o1], a1 = fcb[o2];
        for (int k = 0; k < HH; ++k) {
            const float hv = sh[k];
            const float* fr = fcT + (size_t)k * NS;
            a0 = fmaf(hv, fr[o1], a0);
            a1 = fmaf(hv, fr[o2], a1);
        }
        float l0 = a0 * sigm(a0);
        float l1 = a1 * sigm(a1);
        float mx = block_max4(fmaxf(l0, v2 ? l1 : -3.4e38f), scr);
        float e0 = expf(l0 - mx);
        float e1 = v2 ? expf(l1 - mx) : 0.f;
        float2 s2 = block_sum2_4(e0 + e1, 0.f, scr);
        float w0 = e0 / s2.x, w1 = e1 / s2.x;
        for (int it = 0; it < 30; ++it) {
            float c0v = fminf(fmaxf(w0, 0.f), 0.1f);
            float c1v = fminf(fmaxf(w1, 0.f), 0.1f);
            float lv = (w0 - c0v) + (w1 - c1v);
            float n0 = (c0v != 0.1f) ? c0v : 0.f;
            float n1 = (v2 && c1v != 0.1f) ? c1v : 0.f;
            float2 rs = block_sum2_4(lv, n0 + n1, scr);
            float inv = rs.x / rs.y;
            w0 = c0v + inv * n0;
            w1 = c1v + inv * n1;
        }
        out[(size_t)b * NS + o1] = w0;
        if (v2) out[(size_t)b * NS + tid + 256] = w1;
    }
}

// ---------------- prep: pack x[t=0] ----------------
__global__ void pack_x0(const float* __restrict__ x, ushort_t* __restrict__ xpack) {
    const int t = blockIdx.x * 256 + threadIdx.x;   // 16384 threads
    const int ko = t & 63, b = t >> 6;
    const float* xs = x + (size_t)b * TT * NS;      // t=0
    ushort_t hi8[8], lo8[8];
#pragma unroll
    for (int j = 0; j < 8; ++j) {
        const int k = ko * 8 + j;
        const float v = (k < NS) ? xs[k] : 0.f;
        hi8[j] = f2bf(v);
        lo8[j] = f2bf(v - bf2f(hi8[j]));
    }
    const size_t o = ((size_t)((ko >> 2) * 16 + (b >> 4)) * 64 + (ko & 3) * 16 + (b & 15)) * 8;
    *(uint4*)(xpack + o) = *(uint4*)hi8;
    *(uint4*)(xpack + PL_USH + o) = *(uint4*)lo8;
}

// ---------------- prep: fc weight transpose ----------------
__global__ void transpose_k(const float* __restrict__ src, float* __restrict__ dst,
                            int G, int K) {
    int idx = blockIdx.x * 256 + threadIdx.x;
    if (idx >= G * K) return;
    int k = idx / G, g = idx - k * G;
    dst[idx] = src[(size_t)g * K + k];
}

// ---------------- launch ----------------
extern "C" void kernel_launch(void* const* d_in, const int* in_sizes, int n_in,
                              void* d_out, int out_size, void* d_ws, size_t ws_size,
                              hipStream_t stream) {
    const float* x    = (const float*)d_in[0];
    const float* wih0 = (const float*)d_in[1];
    const float* whh0 = (const float*)d_in[2];
    const float* bih0 = (const float*)d_in[3];
    const float* bhh0 = (const float*)d_in[4];
    const float* wih1 = (const float*)d_in[5];
    const float* whh1 = (const float*)d_in[6];
    const float* bih1 = (const float*)d_in[7];
    const float* bhh1 = (const float*)d_in[8];
    const float* fcw  = (const float*)d_in[9];
    const float* fcb  = (const float*)d_in[10];
    float* outp = (float*)d_out;

    // ws layout (~4.4 MB):
    char* ws = (char*)d_ws;
    unsigned* flags  = (unsigned*)ws;                         // arrival(16KB)+xcd(16.5KB)+elect(32KB) in 196608
    ushort_t* h0pack = (ushort_t*)(ws + 196608);              // 1 MB
    ushort_t* h1pack = (ushort_t*)(ws + 196608 + 1048576);    // 1 MB
    ushort_t* xpack  = (ushort_t*)(ws + 196608 + 2097152);    // 1 MB
    float*    fcT    = (float*)(ws + 196608 + 3145728);       // 512*500*4 = 1024000

    // zero: flags + h packs (h0 = 0 both parities)
    hipMemsetAsync(ws, 0, 196608 + 2097152, stream);
    pack_x0<<<64, 256, 0, stream>>>(x, xpack);
    {
        int nel = NS * HH;
        transpose_k<<<(nel + 255) / 256, 256, 0, stream>>>(fcw, fcT, NS, HH);
    }

    hipFuncSetAttribute((const void*)gru_main,
                        hipFuncAttributeMaxDynamicSharedMemorySize, SMEMB);

    void* args[] = {(void*)&x,
                    (void*)&wih0, (void*)&whh0, (void*)&bih0, (void*)&bhh0,
                    (void*)&wih1, (void*)&whh1, (void*)&bih1, (void*)&bhh1,
                    (void*)&fcb, (void*)&fcT,
                    (void*)&xpack, (void*)&h0pack, (void*)&h1pack,
                    (void*)&flags, (void*)&outp};
    hipError_t e = hipLaunchCooperativeKernel((const void*)gru_main, dim3(NBLK), dim3(TBLK),
                                              args, SMEMB, stream);
    if (e != hipSuccess) {
        gru_main<<<dim3(NBLK), dim3(TBLK), SMEMB, stream>>>(
            x, wih0, whh0, bih0, bhh0, wih1, whh1, bih1, bhh1,
            fcb, fcT, xpack, h0pack, h1pack, flags, outp);
    }
}

// Round 3
// 3330.458 us; speedup vs baseline: 6.3624x; 1.7428x over previous
//
#include <hip/hip_runtime.h>
#include <math.h>

typedef __attribute__((ext_vector_type(8))) short short8;
typedef __attribute__((ext_vector_type(4))) float floatx4;
typedef unsigned short ushort_t;
typedef unsigned int uint32;
typedef unsigned long long u64;

#define BB 256
#define TT 250
#define NS 500
#define HH 512
#define NBLK 256
#define TBLK 256
#define PL_USH 131072u      // act plane: 16ch*16ct*64lane*8 ushorts (512K x 256 bf16)
#define CH_USH 8192u        // act chunk stride: 16ct*64*8
#define WHI_USH 32768
#define SCR_OFF 131072
#define SMEMB (131072 + 2 * 32 * 65 * 4)   // 147712 B

// ---- bf16 split helpers (RNE) ----
__device__ __forceinline__ ushort_t f2bf(float f) {
    uint32 u = __float_as_uint(f);
    u += 0x7fffu + ((u >> 16) & 1u);
    return (ushort_t)(u >> 16);
}
__device__ __forceinline__ float bf2f(ushort_t h) { return __uint_as_float(((uint32)h) << 16); }
__device__ __forceinline__ float sigm(float x) { return 1.f / (1.f + expf(-x)); }
__device__ __forceinline__ floatx4 mfma16(short8 a, short8 b, floatx4 c) {
    return __builtin_amdgcn_mfma_f32_16x16x32_bf16(a, b, c, 0, 0, 0);
}
__device__ __forceinline__ u64 pack4(const ushort_t* a) {
    return (u64)a[0] | ((u64)a[1] << 16) | ((u64)a[2] << 32) | ((u64)a[3] << 48);
}
__device__ __forceinline__ void st_agent_u32(ushort_t* p, uint32 v) {
    __hip_atomic_store((uint32*)p, v, __ATOMIC_RELAXED, __HIP_MEMORY_SCOPE_AGENT);
}
__device__ __forceinline__ void st_agent_u64(ushort_t* p, u64 v) {
    __hip_atomic_store((u64*)p, v, __ATOMIC_RELAXED, __HIP_MEMORY_SCOPE_AGENT);
}

// ------------- pure radix-16 dissemination barrier: 2 rounds, 15 partners/round ---------
// NO cache maintenance anywhere: cross-block data is written sc1 (write-through L3) and
// read with sc0+sc1 loads (L1/L2-bypassing), so no stale copy can exist. Flags are
// relaxed agent atomics (L3-coherent). Monotonic value = phase*2 + round.
__device__ __forceinline__ void dbar(unsigned* flags, unsigned phase, int bid) {
    const int tj = threadIdx.x;
    const unsigned v0 = phase << 1, v1 = (phase << 1) | 1u;
    __syncthreads();   // drains this block's pack stores (vmcnt(0) before s_barrier)
    if (tj == 0)
        __hip_atomic_store(flags + ((size_t)bid << 4), v0,
                           __ATOMIC_RELAXED, __HIP_MEMORY_SCOPE_AGENT);
    if (tj >= 1 && tj < 16) {
        unsigned* sp = flags + ((size_t)((bid - tj) & 255) << 4);
        while (__hip_atomic_load(sp, __ATOMIC_RELAXED, __HIP_MEMORY_SCOPE_AGENT) < v0)
            __builtin_amdgcn_s_sleep(2);
    }
    __syncthreads();
    if (tj == 0)
        __hip_atomic_store(flags + ((size_t)bid << 4), v1,
                           __ATOMIC_RELAXED, __HIP_MEMORY_SCOPE_AGENT);
    if (tj >= 1 && tj < 16) {
        unsigned* sp = flags + ((size_t)((bid - (tj << 4)) & 255) << 4);
        while (__hip_atomic_load(sp, __ATOMIC_RELAXED, __HIP_MEMORY_SCOPE_AGENT) < v1)
            __builtin_amdgcn_s_sleep(2);
    }
    __syncthreads();
}

// ---------------- block reductions (256 thr = 4 waves) ----------------
__device__ __forceinline__ float block_max4(float v, float* scr) {
#pragma unroll
    for (int off = 32; off; off >>= 1) v = fmaxf(v, __shfl_down(v, off, 64));
    if ((threadIdx.x & 63) == 0) scr[threadIdx.x >> 6] = v;
    __syncthreads();
    if (threadIdx.x == 0)
        scr[8] = fmaxf(fmaxf(scr[0], scr[1]), fmaxf(scr[2], scr[3]));
    __syncthreads();
    float r = scr[8];
    __syncthreads();
    return r;
}
__device__ __forceinline__ float2 block_sum2_4(float a, float b, float* scr) {
#pragma unroll
    for (int off = 32; off; off >>= 1) {
        a += __shfl_down(a, off, 64);
        b += __shfl_down(b, off, 64);
    }
    if ((threadIdx.x & 63) == 0) { int w = threadIdx.x >> 6; scr[w] = a; scr[4 + w] = b; }
    __syncthreads();
    if (threadIdx.x == 0) {
        scr[8] = scr[0] + scr[1] + scr[2] + scr[3];
        scr[9] = scr[4] + scr[5] + scr[6] + scr[7];
    }
    __syncthreads();
    float2 r = make_float2(scr[8], scr[9]);
    __syncthreads();
    return r;
}

// ------------- fused gi+gh GEMM: 32 chunks of K=32 ------------------------------------
// Hand-held pipeline: asm global_load_dwordx4 (sc0 sc1 = L1/L2-bypass, L3-fresh) into an
// 8-slot ring (depth 7 = 28 loads in flight), counted s_waitcnt vmcnt(N) + sched_barrier
// before each chunk's MFMAs (compiler cannot sink these loads). Weights double-buffered
// one chunk ahead from LDS.
__device__ __forceinline__ void gemm_both(const ushort_t* __restrict__ gp,
                                          const ushort_t* __restrict__ hp,
                                          const ushort_t* whiS, const ushort_t* wloS,
                                          floatx4 (&aGI)[2][2], floatx4 (&aGH)[2][2]) {
    short8 Bh0[8], Bh1[8], Bl0[8], Bl1[8];
    const ushort_t* gpl = gp + PL_USH;
    const ushort_t* hpl = hp + PL_USH;

#define ISSUE(pc) do {                                                                    \
        const ushort_t* _ph = ((pc) < 16) ? (gp + (size_t)(pc) * CH_USH)                  \
                                          : (hp + (size_t)((pc) - 16) * CH_USH);          \
        const ushort_t* _pl = ((pc) < 16) ? (gpl + (size_t)(pc) * CH_USH)                 \
                                          : (hpl + (size_t)((pc) - 16) * CH_USH);         \
        asm volatile("global_load_dwordx4 %0, %1, off sc0 sc1"                            \
                     : "=v"(Bh0[(pc) & 7]) : "v"(_ph));                                   \
        asm volatile("global_load_dwordx4 %0, %1, off offset:1024 sc0 sc1"                \
                     : "=v"(Bh1[(pc) & 7]) : "v"(_ph));                                   \
        asm volatile("global_load_dwordx4 %0, %1, off sc0 sc1"                            \
                     : "=v"(Bl0[(pc) & 7]) : "v"(_pl));                                   \
        asm volatile("global_load_dwordx4 %0, %1, off offset:1024 sc0 sc1"                \
                     : "=v"(Bl1[(pc) & 7]) : "v"(_pl));                                   \
    } while (0)

    ISSUE(0); ISSUE(1); ISSUE(2); ISSUE(3); ISSUE(4); ISSUE(5); ISSUE(6);

    short8 w0h = *(const short8*)(whiS);
    short8 w1h = *(const short8*)(whiS + 512);
    short8 w0l = *(const short8*)(wloS);
    short8 w1l = *(const short8*)(wloS + 512);

#define GSTEP(c, N) do {                                                                  \
        if ((c) + 7 < 32) ISSUE((c) + 7);                                                 \
        short8 n0h, n1h, n0l, n1l;                                                        \
        if ((c) + 1 < 32) {                                                               \
            const size_t _w = (size_t)(((c) + 1) * 2) * 512;                              \
            n0h = *(const short8*)(whiS + _w);                                            \
            n1h = *(const short8*)(whiS + _w + 512);                                      \
            n0l = *(const short8*)(wloS + _w);                                            \
            n1l = *(const short8*)(wloS + _w + 512);                                      \
        }                                                                                 \
        asm volatile("s_waitcnt vmcnt(" #N ")" ::: "memory");                             \
        __builtin_amdgcn_sched_barrier(0);                                                \
        const int _cs = (c) & 7;                                                          \
        floatx4 (&A)[2][2] = ((c) < 16) ? aGI : aGH;                                      \
        A[0][0] = mfma16(w0h, Bh0[_cs], A[0][0]);                                         \
        A[0][1] = mfma16(w0h, Bh1[_cs], A[0][1]);                                         \
        A[1][0] = mfma16(w1h, Bh0[_cs], A[1][0]);                                         \
        A[1][1] = mfma16(w1h, Bh1[_cs], A[1][1]);                                         \
        A[0][0] = mfma16(w0h, Bl0[_cs], A[0][0]);                                         \
        A[0][1] = mfma16(w0h, Bl1[_cs], A[0][1]);                                         \
        A[1][0] = mfma16(w1h, Bl0[_cs], A[1][0]);                                         \
        A[1][1] = mfma16(w1h, Bl1[_cs], A[1][1]);                                         \
        A[0][0] = mfma16(w0l, Bh0[_cs], A[0][0]);                                         \
        A[0][1] = mfma16(w0l, Bh1[_cs], A[0][1]);                                         \
        A[1][0] = mfma16(w1l, Bh0[_cs], A[1][0]);                                         \
        A[1][1] = mfma16(w1l, Bh1[_cs], A[1][1]);                                         \
        if ((c) + 1 < 32) { w0h = n0h; w1h = n1h; w0l = n0l; w1l = n1l; }                 \
    } while (0)

    GSTEP(0, 28);  GSTEP(1, 28);  GSTEP(2, 28);  GSTEP(3, 28);  GSTEP(4, 28);
    GSTEP(5, 28);  GSTEP(6, 28);  GSTEP(7, 28);  GSTEP(8, 28);  GSTEP(9, 28);
    GSTEP(10, 28); GSTEP(11, 28); GSTEP(12, 28); GSTEP(13, 28); GSTEP(14, 28);
    GSTEP(15, 28); GSTEP(16, 28); GSTEP(17, 28); GSTEP(18, 28); GSTEP(19, 28);
    GSTEP(20, 28); GSTEP(21, 28); GSTEP(22, 28); GSTEP(23, 28); GSTEP(24, 28);
    GSTEP(25, 24); GSTEP(26, 20); GSTEP(27, 16); GSTEP(28, 12); GSTEP(29, 8);
    GSTEP(30, 4);  GSTEP(31, 0);
#undef GSTEP
#undef ISSUE
}

// ---------------- main persistent kernel ----------------
// 256 blocks = L(2) x UG(64 groups of 8 units) x CT(2 col-halves of 128).
__global__ void __launch_bounds__(TBLK, 1)
gru_main(const float* __restrict__ x,
         const float* __restrict__ wih0, const float* __restrict__ whh0,
         const float* __restrict__ bi0,  const float* __restrict__ bh0,
         const float* __restrict__ wih1, const float* __restrict__ whh1,
         const float* __restrict__ bi1,  const float* __restrict__ bh1,
         const float* __restrict__ fcb,  const float* __restrict__ fcT,
         ushort_t* xpack, ushort_t* h0pack, ushort_t* h1pack,
         unsigned* flags,
         float* __restrict__ out)
{
    extern __shared__ char smem_raw[];
    ushort_t* whi = (ushort_t*)smem_raw;            // 32768 ush (64 KB)
    ushort_t* wlo = whi + WHI_USH;                  // 64 KB
    float* scrF = (float*)(smem_raw + SCR_OFF);     // [2][32][65] floats

    const int bid = blockIdx.x, tid = threadIdx.x;
    const int L  = bid >> 7;
    const int UG = (bid >> 1) & 63;      // 8-unit group
    const int CT = bid & 1;              // col half (128 batches)
    const int wid = tid >> 6, lane = tid & 63;
    const int q = lane >> 4, n = lane & 15;

    // ---- stage this block's weights into LDS (hi+lo planes, A-frag layout) ----
    {
        const float* Wgi = L ? wih1 : wih0;
        const float* Wgh = L ? whh1 : whh0;
        const int Kgi = L ? HH : NS;
        for (int idx = tid; idx < 32768; idx += TBLK) {
            const int j = idx & 7, ln = (idx >> 3) & 63, rc = idx >> 9;  // rc = wc*2+rt
            const int c = rc >> 1, rt = rc & 1;
            const int m = ln & 15, qq = ln >> 4;
            const int lr = rt * 16 + m;          // 0..31 (rows 24..31 pad)
            const int g = lr >> 3, u = lr & 7;
            float v = 0.f;
            if (g < 3) {
                if (c < 16) {
                    const int k = c * 32 + qq * 8 + j;
                    if (k < Kgi) v = Wgi[(size_t)(g * HH + UG * 8 + u) * Kgi + k];
                } else {
                    const int k = (c - 16) * 32 + qq * 8 + j;
                    v = Wgh[(size_t)(g * HH + UG * 8 + u) * HH + k];
                }
            }
            const ushort_t hb = f2bf(v);
            whi[idx] = hb;
            wlo[idx] = f2bf(v - bf2f(hb));
        }
    }

    // per-thread elementwise assignment: units u2,u2+1; cols h*64 + lb (h=round)
    const int lb = tid & 63, u2 = (tid >> 6) * 2;
    float biR[2], biZ[2], biN[2], bhR[2], bhZ[2], bhN[2];
    {
        const float* bi = L ? bi1 : bi0;
        const float* bh = L ? bh1 : bh0;
#pragma unroll
        for (int p = 0; p < 2; ++p) {
            const int ugl = UG * 8 + u2 + p;
            biR[p] = bi[ugl]; biZ[p] = bi[HH + ugl]; biN[p] = bi[2 * HH + ugl];
            bhR[p] = bh[ugl]; bhZ[p] = bh[HH + ugl]; bhN[p] = bh[2 * HH + ugl];
        }
    }
    float hreg[4] = {0.f, 0.f, 0.f, 0.f};   // [round h][p]
    const int chW = UG >> 2, qqW = UG & 3;  // pack-write constants
    __syncthreads();

    const ushort_t* whiS = whi + (size_t)lane * 8;
    const ushort_t* wloS = wlo + (size_t)lane * 8;
    const size_t apoff = ((size_t)(CT * 8 + wid * 2) * 64 + lane) * 8;

    unsigned phase = 0;
    for (int s = 0; s <= TT; ++s) {
        const bool active = L ? (s >= 1) : (s < TT);
        if (active) {
            const ushort_t *gisrc, *ghsrc;
            if (L == 0) {
                gisrc = xpack + (size_t)(s & 1) * 2 * PL_USH;
                ghsrc = h0pack + (size_t)((s - 1) & 1) * 2 * PL_USH;
            } else {
                gisrc = h0pack + (size_t)((s - 1) & 1) * 2 * PL_USH;
                ghsrc = h1pack + (size_t)(s & 1) * 2 * PL_USH;
            }
            floatx4 z4 = {0.f, 0.f, 0.f, 0.f};
            floatx4 aGI[2][2], aGH[2][2];
#pragma unroll
            for (int i = 0; i < 2; ++i) { aGI[i][0] = z4; aGI[i][1] = z4; aGH[i][0] = z4; aGH[i][1] = z4; }
            gemm_both(gisrc + apoff, ghsrc + apoff, whiS, wloS, aGI, aGH);

            // ---- x staging loads for step s+1 (issue early, store later) ----
            float4 xv0, xv1;
            const bool doX = (s <= TT - 2) && (bid * TBLK + tid < 16384);
            int xko = 0, xb = 0;
            if (doX) {
                const int gx = bid * TBLK + tid;
                xko = gx & 63; xb = gx >> 6;
                const float* xs = x + ((size_t)xb * TT + (s + 1)) * NS + xko * 8;
                if (xko < 62) { xv0 = *(const float4*)(xs); xv1 = *(const float4*)(xs + 4); }
                else {
                    float tmp[8];
#pragma unroll
                    for (int j = 0; j < 8; ++j) {
                        const int k = xko * 8 + j;
                        tmp[j] = (k < NS) ? xs[j] : 0.f;
                    }
                    xv0 = make_float4(tmp[0], tmp[1], tmp[2], tmp[3]);
                    xv1 = make_float4(tmp[4], tmp[5], tmp[6], tmp[7]);
                }
            }

            // ---- elementwise in two col-rounds through LDS scratch ----
            ushort_t* pk = L ? h1pack + (size_t)((s - 1) & 1) * 2 * PL_USH
                             : h0pack + (size_t)(s & 1) * 2 * PL_USH;
#pragma unroll
            for (int h = 0; h < 2; ++h) {
                if ((wid >> 1) == h) {
#pragma unroll
                    for (int rt = 0; rt < 2; ++rt)
#pragma unroll
                        for (int t = 0; t < 2; ++t) {
                            const int row0 = rt * 16 + q * 4;
                            const int colr = ((wid & 1) * 2 + t) * 16 + n;
#pragma unroll
                            for (int r4 = 0; r4 < 4; ++r4) {
                                scrF[(row0 + r4) * 65 + colr] = aGI[rt][t][r4];
                                scrF[2080 + (row0 + r4) * 65 + colr] = aGH[rt][t][r4];
                            }
                        }
                }
                __syncthreads();
                float hvv[2];
#pragma unroll
                for (int p = 0; p < 2; ++p) {
                    const int u = u2 + p;
                    const float gir = scrF[u * 65 + lb],        ghr = scrF[2080 + u * 65 + lb];
                    const float giz = scrF[(8 + u) * 65 + lb],  ghz = scrF[2080 + (8 + u) * 65 + lb];
                    const float gin = scrF[(16 + u) * 65 + lb], ghn = scrF[2080 + (16 + u) * 65 + lb];
                    const float rr = sigm(gir + biR[p] + ghr + bhR[p]);
                    const float zz = sigm(giz + biZ[p] + ghz + bhZ[p]);
                    const float nn = tanhf(gin + biN[p] + rr * (ghn + bhN[p]));
                    const float hv = (1.f - zz) * nn + zz * hreg[h * 2 + p];
                    hreg[h * 2 + p] = hv;
                    hvv[p] = hv;
                }
                // paired write-through stores (p0|p1 in one dword per plane)
                {
                    const int b = CT * 128 + h * 64 + lb;
                    const size_t o8 = ((size_t)(chW * 16 + (b >> 4)) * 64 + qqW * 16 + (b & 15)) * 8;
                    const ushort_t hb0 = f2bf(hvv[0]), hb1 = f2bf(hvv[1]);
                    const uint32 hi2 = (uint32)hb0 | ((uint32)hb1 << 16);
                    const uint32 lo2 = (uint32)f2bf(hvv[0] - bf2f(hb0)) |
                                       ((uint32)f2bf(hvv[1] - bf2f(hb1)) << 16);
                    st_agent_u32(pk + o8 + u2, hi2);
                    st_agent_u32(pk + PL_USH + o8 + u2, lo2);
                }
                __syncthreads();
            }

            // ---- x staging stores (write-through) ----
            if (doX) {
                ushort_t hi8[8], lo8[8];
                float vv[8] = {xv0.x, xv0.y, xv0.z, xv0.w, xv1.x, xv1.y, xv1.z, xv1.w};
#pragma unroll
                for (int j = 0; j < 8; ++j) {
                    hi8[j] = f2bf(vv[j]);
                    lo8[j] = f2bf(vv[j] - bf2f(hi8[j]));
                }
                ushort_t* xp = xpack + (size_t)((s + 1) & 1) * 2 * PL_USH;
                const size_t o = ((size_t)((xko >> 2) * 16 + (xb >> 4)) * 64 + (xko & 3) * 16 + (xb & 15)) * 8;
                st_agent_u64(xp + o, pack4(hi8));
                st_agent_u64(xp + o + 4, pack4(hi8 + 4));
                st_agent_u64(xp + PL_USH + o, pack4(lo8));
                st_agent_u64(xp + PL_USH + o + 4, pack4(lo8 + 4));
            }
        } else if ((s <= TT - 2) && (bid * TBLK + tid < 16384)) {
            // inactive blocks still stage x
            const int gx = bid * TBLK + tid;
            const int xko = gx & 63, xb = gx >> 6;
            const float* xs = x + ((size_t)xb * TT + (s + 1)) * NS + xko * 8;
            ushort_t hi8[8], lo8[8];
#pragma unroll
            for (int j = 0; j < 8; ++j) {
                const int k = xko * 8 + j;
                const float v = (k < NS) ? xs[j] : 0.f;
                hi8[j] = f2bf(v);
                lo8[j] = f2bf(v - bf2f(hi8[j]));
            }
            ushort_t* xp = xpack + (size_t)((s + 1) & 1) * 2 * PL_USH;
            const size_t o = ((size_t)((xko >> 2) * 16 + (xb >> 4)) * 64 + (xko & 3) * 16 + (xb & 15)) * 8;
            st_agent_u64(xp + o, pack4(hi8));
            st_agent_u64(xp + o + 4, pack4(hi8 + 4));
            st_agent_u64(xp + PL_USH + o, pack4(lo8));
            st_agent_u64(xp + PL_USH + o + 4, pack4(lo8 + 4));
        }
        ++phase;
        dbar(flags, phase, bid);
    }

    // ================= epilogue: FC + silu + softmax + rebalance (block = batch) =========
    {
        const int b = bid;
        float* sh = (float*)smem_raw;       // 512 floats
        float* scr = sh + 576;
        const ushort_t* pk = h1pack + (size_t)1 * 2 * PL_USH;   // h1[249], parity 1
        for (int u = tid; u < HH; u += TBLK) {
            const int uo = u >> 3, j = u & 7;
            const size_t o = ((size_t)((uo >> 2) * 16 + (b >> 4)) * 64 + (uo & 3) * 16 + (b & 15)) * 8 + j;
            sh[u] = bf2f(pk[o]) + bf2f(pk[PL_USH + o]);
        }
        __syncthreads();

        const int o1 = tid;
        const bool v2 = (tid + 256) < NS;
        const int o2 = v2 ? (tid + 256) : (NS - 1);
        float a0 = fcb[o1], a1 = fcb[o2];
        for (int k = 0; k < HH; ++k) {
            const float hv = sh[k];
            const float* fr = fcT + (size_t)k * NS;
            a0 = fmaf(hv, fr[o1], a0);
            a1 = fmaf(hv, fr[o2], a1);
        }
        float l0 = a0 * sigm(a0);
        float l1 = a1 * sigm(a1);
        float mx = block_max4(fmaxf(l0, v2 ? l1 : -3.4e38f), scr);
        float e0 = expf(l0 - mx);
        float e1 = v2 ? expf(l1 - mx) : 0.f;
        float2 s2 = block_sum2_4(e0 + e1, 0.f, scr);
        float w0 = e0 / s2.x, w1 = e1 / s2.x;
        for (int it = 0; it < 30; ++it) {
            float c0v = fminf(fmaxf(w0, 0.f), 0.1f);
            float c1v = fminf(fmaxf(w1, 0.f), 0.1f);
            float lv = (w0 - c0v) + (w1 - c1v);
            float n0 = (c0v != 0.1f) ? c0v : 0.f;
            float n1 = (v2 && c1v != 0.1f) ? c1v : 0.f;
            float2 rs = block_sum2_4(lv, n0 + n1, scr);
            float inv = rs.x / rs.y;
            w0 = c0v + inv * n0;
            w1 = c1v + inv * n1;
        }
        out[(size_t)b * NS + o1] = w0;
        if (v2) out[(size_t)b * NS + tid + 256] = w1;
    }
}

// ---------------- prep: pack x[t=0] ----------------
__global__ void pack_x0(const float* __restrict__ x, ushort_t* __restrict__ xpack) {
    const int t = blockIdx.x * 256 + threadIdx.x;   // 16384 threads
    const int ko = t & 63, b = t >> 6;
    const float* xs = x + (size_t)b * TT * NS;      // t=0
    ushort_t hi8[8], lo8[8];
#pragma unroll
    for (int j = 0; j < 8; ++j) {
        const int k = ko * 8 + j;
        const float v = (k < NS) ? xs[k] : 0.f;
        hi8[j] = f2bf(v);
        lo8[j] = f2bf(v - bf2f(hi8[j]));
    }
    const size_t o = ((size_t)((ko >> 2) * 16 + (b >> 4)) * 64 + (ko & 3) * 16 + (b & 15)) * 8;
    *(uint4*)(xpack + o) = *(uint4*)hi8;
    *(uint4*)(xpack + PL_USH + o) = *(uint4*)lo8;
}

// ---------------- prep: fc weight transpose ----------------
__global__ void transpose_k(const float* __restrict__ src, float* __restrict__ dst,
                            int G, int K) {
    int idx = blockIdx.x * 256 + threadIdx.x;
    if (idx >= G * K) return;
    int k = idx / G, g = idx - k * G;
    dst[idx] = src[(size_t)g * K + k];
}

// ---------------- launch ----------------
extern "C" void kernel_launch(void* const* d_in, const int* in_sizes, int n_in,
                              void* d_out, int out_size, void* d_ws, size_t ws_size,
                              hipStream_t stream) {
    const float* x    = (const float*)d_in[0];
    const float* wih0 = (const float*)d_in[1];
    const float* whh0 = (const float*)d_in[2];
    const float* bih0 = (const float*)d_in[3];
    const float* bhh0 = (const float*)d_in[4];
    const float* wih1 = (const float*)d_in[5];
    const float* whh1 = (const float*)d_in[6];
    const float* bih1 = (const float*)d_in[7];
    const float* bhh1 = (const float*)d_in[8];
    const float* fcw  = (const float*)d_in[9];
    const float* fcb  = (const float*)d_in[10];
    float* outp = (float*)d_out;

    // ws layout (~4.4 MB):
    char* ws = (char*)d_ws;
    unsigned* flags  = (unsigned*)ws;                         // 256*64B used (region 196608)
    ushort_t* h0pack = (ushort_t*)(ws + 196608);              // 1 MB
    ushort_t* h1pack = (ushort_t*)(ws + 196608 + 1048576);    // 1 MB
    ushort_t* xpack  = (ushort_t*)(ws + 196608 + 2097152);    // 1 MB
    float*    fcT    = (float*)(ws + 196608 + 3145728);       // 512*500*4 = 1024000

    // zero: flags + h packs (h0 = 0 both parities)
    hipMemsetAsync(ws, 0, 196608 + 2097152, stream);
    pack_x0<<<64, 256, 0, stream>>>(x, xpack);
    {
        int nel = NS * HH;
        transpose_k<<<(nel + 255) / 256, 256, 0, stream>>>(fcw, fcT, NS, HH);
    }

    hipFuncSetAttribute((const void*)gru_main,
                        hipFuncAttributeMaxDynamicSharedMemorySize, SMEMB);

    void* args[] = {(void*)&x,
                    (void*)&wih0, (void*)&whh0, (void*)&bih0, (void*)&bhh0,
                    (void*)&wih1, (void*)&whh1, (void*)&bih1, (void*)&bhh1,
                    (void*)&fcb, (void*)&fcT,
                    (void*)&xpack, (void*)&h0pack, (void*)&h1pack,
                    (void*)&flags, (void*)&outp};
    hipError_t e = hipLaunchCooperativeKernel((const void*)gru_main, dim3(NBLK), dim3(TBLK),
                                              args, SMEMB, stream);
    if (e != hipSuccess) {
        gru_main<<<dim3(NBLK), dim3(TBLK), SMEMB, stream>>>(
            x, wih0, whh0, bih0, bhh0, wih1, whh1, bih1, bhh1,
            fcb, fcT, xpack, h0pack, h1pack, flags, outp);
    }
}